// Round 13
// baseline (169.342 us; speedup 1.0000x reference)
//
#include <hip/hip_runtime.h>
#include <hip/hip_bf16.h>

// PairwiseScore round 13: R12 structure with K-chunk 128 (10 fat phases, was
// 38) — at 1 wave/SIMD the per-barrier drain is the dominant loss, so spend
// LDS (137KB dbuf) to cut barrier count 4x. Same swizzles/numerics as R12.
//   h1 = relu(gi@W1a + gj@W1b + (gi.gj)@W1c + b1)   [A/B precomp per mention]
//   out = relu(h1@W2 + b2) @ W3 + b3
// Shapes: M=10000, D=1200(->1280), P=2000, K=50, H=150(->160), NP=98725.

typedef __attribute__((ext_vector_type(8))) short short8;
typedef __attribute__((ext_vector_type(4))) float f32x4;

constexpr int DP    = 1280;      // padded G_DIM (10*128)
constexpr int HPAD  = 160;       // padded hidden
constexpr int NPH   = 10;        // K-phases of 128 over DP (pair kernel)
constexpr int NKCP  = 38;        // K-chunks of 32 (precomp kernel)
constexpr int NIMG  = 40;        // 32-wide sub-images over DP
constexpr int NKC2  = 5;         // K-chunks of 32 over HPAD
constexpr int WCH1  = 5120;      // ushorts per 32-k hi W sub-image
constexpr int KD    = 50;        // compile-time K
constexpr int TI    = 5;         // i's per dense block
constexpr int PB    = TI * KD;   // 250 pairs per dense block
constexpr int NGR   = KD + TI;   // 55 staged G rows
constexpr int TD    = KD * (KD - 1) / 2;  // 1225 head pairs

// smem layout (bytes)
constexpr int OFF_WB0 = 0;          // [40960] W phase buf 0
constexpr int OFF_WB1 = 40960;      // [40960] W phase buf 1
constexpr int OFF_GS0 = 81920;      // [28672] G window buf 0 (1792 x 16B)
constexpr int OFF_GS1 = 110592;     // [28672] G window buf 1
constexpr int OFF_TI  = 139264;     // [512]
constexpr int OFF_TJ  = 139776;     // [512]
constexpr int SMEM_SZ = 140288;

__device__ __forceinline__ ushort bf16_rne(float x) {
  uint u = __float_as_uint(x);
  u += 0x7FFFu + ((u >> 16) & 1u);
  return (ushort)(u >> 16);
}
__device__ __forceinline__ float bf16f(ushort h) {
  return __uint_as_float((uint)h << 16);
}
__device__ __forceinline__ f32x4 mfma16(short8 a, short8 b, f32x4 c) {
  return __builtin_amdgcn_mfma_f32_16x16x32_bf16(a, b, c, 0, 0, 0);
}
__device__ __forceinline__ void g2lds16(const void* g, void* l) {
  __builtin_amdgcn_global_load_lds(
      (const __attribute__((address_space(1))) void*)g,
      (__attribute__((address_space(3))) void*)l, 16, 0, 0);
}
// stage a 40960B W phase image (4 x 5120-ushort sub-images), 4 waves
__device__ __forceinline__ void stage_W128(const ushort* gs, ushort* lb,
                                           int w, int lane) {
  const char* g = (const char*)gs + w * 1024 + lane * 16;
  char* l = (char*)lb + w * 1024;
#pragma unroll
  for (int r = 0; r < 10; ++r) g2lds16(g + r * 4096, l + r * 4096);
}
// stage a 10240B hi-only 32-k W chunk (4 waves) — phase-2 / precomp path
__device__ __forceinline__ void stage_hi(const ushort* gs, ushort* lb,
                                         int w, int lane) {
  const char* g = (const char*)gs + w * 1024 + lane * 16;
  char* l = (char*)lb + w * 1024;
  g2lds16(g, l);
  g2lds16(g + 4096, l + 4096);
  if (w < 2) g2lds16(g + 8192, l + 8192);
}
// stage the 55-row x 128-col f32 G slice (phase c), inverse-XOR source.
// slot = row*32 + g5 (g5 = which float4 of the row); swizzle low 3 bits of g5.
__device__ __forceinline__ void stage_G128(const float* __restrict__ G, int b0,
                                           int c, float* buf, int w, int lane) {
#pragma unroll
  for (int r = 0; r < 7; ++r) {
    const int slot = r * 256 + w * 64 + lane;
    int row = slot >> 5, g5 = slot & 31;
    row = min(row, NGR - 1);
    const float* src = G + (size_t)(b0 + row) * DP + c * 128 +
                       (((g5 & 24) | ((g5 & 7) ^ (row & 7))) << 2);
    g2lds16(src, (char*)buf + slot * 16);  // wave-uniform base + lane*16
  }
}
// products (8 elems) -> bf16 RNE via hardware cvt_pk
__device__ __forceinline__ short8 mulcvt8(float4 a0, float4 a1, float4 b0,
                                          float4 b1) {
  float p[8] = {a0.x * b0.x, a0.y * b0.y, a0.z * b0.z, a0.w * b0.w,
                a1.x * b1.x, a1.y * b1.y, a1.z * b1.z, a1.w * b1.w};
  uint r[4];
#pragma unroll
  for (int e = 0; e < 4; ++e) {
    __hip_bfloat162 t = __float22bfloat162_rn(make_float2(p[2 * e], p[2 * e + 1]));
    r[e] = *(uint*)&t;
  }
  uint4 h = make_uint4(r[0], r[1], r[2], r[3]);
  return *(short8*)&h;
}
// exact hi/lo split of raw values (precomp path)
__device__ __forceinline__ void split1(const float* a, short8& hi, short8& lo) {
  const float4 a0 = *(const float4*)a, a1 = *(const float4*)(a + 4);
  float p[8] = {a0.x, a0.y, a0.z, a0.w, a1.x, a1.y, a1.z, a1.w};
  uint h[4], l[4];
#pragma unroll
  for (int e = 0; e < 4; ++e) {
    uint u0 = __float_as_uint(p[2 * e]), u1 = __float_as_uint(p[2 * e + 1]);
    float r0 = p[2 * e] - __uint_as_float(u0 & 0xffff0000u);
    float r1 = p[2 * e + 1] - __uint_as_float(u1 & 0xffff0000u);
    h[e] = __builtin_amdgcn_perm(u1, u0, 0x07060302u);
    l[e] = __builtin_amdgcn_perm(__float_as_uint(r1), __float_as_uint(r0),
                                 0x07060302u);
  }
  uint4 hu = make_uint4(h[0], h[1], h[2], h[3]);
  uint4 lu = make_uint4(l[0], l[1], l[2], l[3]);
  hi = *(short8*)&hu; lo = *(short8*)&lu;
}
__device__ __forceinline__ void pair_ij(int r, int K, int NP, int& i, int& j) {
  if (r >= NP) { i = 1; j = 0; return; }
  const int T = K * (K - 1) / 2;
  if (r < T) {
    int ii = (int)((1.0f + sqrtf(1.0f + 8.0f * (float)r)) * 0.5f);
    while (ii * (ii - 1) / 2 > r) --ii;
    while ((ii + 1) * ii / 2 <= r) ++ii;
    i = ii; j = r - ii * (ii - 1) / 2;
  } else {
    const int rp = r - T, q = rp / K;
    i = K + q; j = i - K + (rp - q * K);
  }
}

// ---------- k_prep_gather: fused weight prep + G gather ----------
// W1ab_hi: [2 slabs][38][5120] swizzled hi (precomp); W1c_hi: [40][5120]
// (pair, zeros k>=1200); W2_hi: [5][5120].
__global__ void k_prep_gather(const float* __restrict__ W1,
                              const float* __restrict__ W2,
                              const float* __restrict__ M,
                              const int* __restrict__ pidx,
                              ushort* __restrict__ W1ab_hi,
                              ushort* __restrict__ W1c_hi,
                              ushort* __restrict__ W2_hi,
                              float* __restrict__ G, int P) {
  if ((int)blockIdx.x < P) {
    const int i = blockIdx.x;
    const int r = pidx[i];
    const float4* src = reinterpret_cast<const float4*>(M + (size_t)r * 1200);
    float4* dst = reinterpret_cast<float4*>(G + (size_t)i * DP);
    for (int t = threadIdx.x; t < DP / 4; t += blockDim.x)
      dst[t] = (t < 300) ? src[t] : make_float4(0.f, 0.f, 0.f, 0.f);
    return;
  }
  const int NAB = 2 * NKCP * HPAD * 32;
  const int NC = NIMG * HPAD * 32;
  int idx = (blockIdx.x - P) * 256 + threadIdx.x;
  if (idx < NAB) {
    int s = idx / (NKCP * HPAD * 32), r1 = idx % (NKCP * HPAD * 32);
    int c = r1 / (HPAD * 32), r2 = r1 % (HPAD * 32);
    int col = r2 >> 5, kk = r2 & 31;
    int k = c * 32 + kk;
    float v = (k < 1200 && col < 150) ? W1[((size_t)s * 1200 + k) * 150 + col] : 0.f;
    int i0 = (col * 32 + kk) ^ ((col & 7) << 3);
    W1ab_hi[(size_t)(s * NKCP + c) * WCH1 + i0] = bf16_rne(v);
  } else if (idx < NAB + NC) {
    int r1 = idx - NAB;
    int c = r1 / (HPAD * 32), r2 = r1 % (HPAD * 32);
    int col = r2 >> 5, kk = r2 & 31;
    int k = c * 32 + kk;
    float v = (k < 1200 && col < 150)
                  ? W1[((size_t)2 * 1200 + k) * 150 + col] : 0.f;
    int i0 = (col * 32 + kk) ^ ((col & 7) << 3);
    W1c_hi[(size_t)c * WCH1 + i0] = bf16_rne(v);
  } else {
    int r1 = idx - NAB - NC;
    if (r1 < NKC2 * HPAD * 32) {
      int c = r1 / (HPAD * 32), r2 = r1 % (HPAD * 32);
      int col = r2 >> 5, kk = r2 & 31;
      int k = c * 32 + kk;
      float v = (k < 150 && col < 150) ? W2[(size_t)k * 150 + col] : 0.f;
      int i0 = (col * 32 + kk) ^ ((col & 7) << 3);
      W2_hi[(size_t)c * WCH1 + i0] = bf16_rne(v);
    }
  }
}

// ---------- k_precomp: AB[slab][r][col] = G[r]@W1slab (+b1 if slab0), 2-term ----------
__global__ __launch_bounds__(256, 4) void k_precomp(
    const float* __restrict__ G, const ushort* __restrict__ W1ab_hi,
    const float* __restrict__ b1, float* __restrict__ AB, int P) {
  __shared__ __align__(16) ushort Wb[2][WCH1];
  const int tid = threadIdx.x, lane = tid & 63, w = tid >> 6;
  const int l15 = lane & 15, kb = lane >> 4;
  const int rt = w & 1, ch = w >> 1;
  const int r0 = blockIdx.x * 32;
  const int slab = blockIdx.y;
  const ushort* wsrc = W1ab_hi + (size_t)slab * NKCP * WCH1;

  const int row = min(r0 + rt * 16 + l15, P - 1);
  const float* g = G + (size_t)row * DP + kb * 8;
  const int lbase = (l15 * 32 + kb * 8) ^ ((l15 & 7) << 3);

  f32x4 acc[5];
#pragma unroll
  for (int b = 0; b < 5; ++b) acc[b] = (f32x4)(0.f);

  stage_hi(wsrc, Wb[0], w, lane);
  short8 ah, al;
  split1(g, ah, al);

  for (int c = 0; c < NKCP; ++c) {
    __syncthreads();
    if (c < NKCP - 1)
      stage_hi(wsrc + (size_t)(c + 1) * WCH1, Wb[(c + 1) & 1], w, lane);
    const ushort* wb = Wb[c & 1];
#pragma unroll
    for (int ct = 0; ct < 5; ++ct) {
      const short8 bh = *(const short8*)&wb[(ch * 5 + ct) * 512 + lbase];
      acc[ct] = mfma16(ah, bh, acc[ct]);
      acc[ct] = mfma16(al, bh, acc[ct]);
    }
    if (c < NKCP - 1) split1(g + (c + 1) * 32, ah, al);
  }
  float* outp = AB + (size_t)slab * P * HPAD;
#pragma unroll
  for (int q = 0; q < 4; ++q) {
    const int r = r0 + rt * 16 + kb * 4 + q;
    if (r < P) {
#pragma unroll
      for (int ct = 0; ct < 5; ++ct) {
        const int col = (ch * 5 + ct) * 16 + l15;
        float v = acc[ct][q];
        if (slab == 0 && col < 150) v += b1[col];
        outp[(size_t)r * HPAD + col] = v;
      }
    }
  }
}

// ---------- k_pair: dense (bx<ND) + gen head (bx>=ND); K=128 phases; fused MLP ----------
__global__ __launch_bounds__(256, 1) void k_pair(
    const float* __restrict__ G, const ushort* __restrict__ W1c_hi,
    const ushort* __restrict__ W2_hi, const float* __restrict__ AB,
    const float* __restrict__ b2, const float* __restrict__ W3,
    const float* __restrict__ b3, ushort* __restrict__ H1,
    float* __restrict__ out, int P, int K, int NP, int ND, int wlimHead) {
  __shared__ __align__(16) char smem[SMEM_SZ];
  ushort* Wb0 = (ushort*)(smem + OFF_WB0);
  ushort* Wb1 = (ushort*)(smem + OFF_WB1);
  float*  Gs0 = (float*)(smem + OFF_GS0);
  float*  Gs1 = (float*)(smem + OFF_GS1);
  int* tI = (int*)(smem + OFF_TI);
  int* tJ = (int*)(smem + OFF_TJ);

  const int tid = threadIdx.x, lane = tid & 63, w = tid >> 6;
  const int l15 = lane & 15, kb = lane >> 4;
  const int lswz = (l15 * 32 + kb * 8) ^ ((l15 & 7) << 3);
  const float* ABB = AB + (size_t)P * HPAD;

  if ((int)blockIdx.x < ND) {
    // ======== dense: TI=5 i's, 250 pairs, 4 waves x 4 rt x 16 rows ========
    const int q8 = ND >> 3, r8 = ND & 7;
    const int xcd = blockIdx.x & 7, sidx = blockIdx.x >> 3;
    const int bid = (xcd < r8) ? xcd * (q8 + 1) + sidx
                               : r8 * (q8 + 1) + (xcd - r8) * q8 + sidx;
    const int i0 = KD + bid * TI;
    const int b0 = i0 - KD;
    ushort* H1blk = H1 + (size_t)(TD + (size_t)bid * PB) * HPAD;

    // base slots (ks=0); slot(row,g5) = row*32 + (g5&24)|((g5&7)^(row&7));
    // second float4 of a pair = ^1; ks advance = +8.
    uint sI[4], sJ[4];
#pragma unroll
    for (int rt = 0; rt < 4; ++rt) {
      const int q = min(w * 64 + rt * 16 + l15, PB - 1);
      const int li = KD + q / KD, lj = q / KD + q % KD;
      sI[rt] = li * 32 + ((2 * kb) ^ (li & 7));
      sJ[rt] = lj * 32 + ((2 * kb) ^ (lj & 7));
    }

    {
      f32x4 acc[4][10];
#pragma unroll
      for (int a = 0; a < 4; ++a)
#pragma unroll
        for (int b = 0; b < 10; ++b) acc[a][b] = (f32x4)(0.f);

      stage_G128(G, b0, 0, Gs0, w, lane);
      stage_W128(W1c_hi, Wb0, w, lane);
      __syncthreads();

      for (int c = 0; c < NPH; ++c) {
        if (c) __syncthreads();
        if (c < NPH - 1) {
          stage_G128(G, b0, c + 1, (c & 1) ? Gs0 : Gs1, w, lane);
          stage_W128(W1c_hi + (size_t)(c + 1) * 4 * WCH1, (c & 1) ? Wb0 : Wb1,
                     w, lane);
        }
        const float4* gp = (const float4*)((c & 1) ? Gs1 : Gs0);
        const ushort* wb = (c & 1) ? Wb1 : Wb0;
#pragma unroll
        for (int ks = 0; ks < 4; ++ks) {
          short8 a[4];
#pragma unroll
          for (int rt = 0; rt < 4; ++rt) {
            const uint si = sI[rt] + ks * 8, sj = sJ[rt] + ks * 8;
            a[rt] = mulcvt8(gp[si], gp[si ^ 1], gp[sj], gp[sj ^ 1]);
          }
          const ushort* wks = wb + ks * WCH1;
#pragma unroll
          for (int ct = 0; ct < 10; ++ct) {
            const short8 bh = *(const short8*)&wks[ct * 512 + lswz];
            acc[0][ct] = mfma16(a[0], bh, acc[0][ct]);
            acc[1][ct] = mfma16(a[1], bh, acc[1][ct]);
            acc[2][ct] = mfma16(a[2], bh, acc[2][ct]);
            acc[3][ct] = mfma16(a[3], bh, acc[3][ct]);
          }
        }
      }

      // ---- phase1 epilogue: h1 = relu(acc + A[i] + B[j]) -> H1 (last acc use) ----
#pragma unroll
      for (int rt = 0; rt < 4; ++rt)
#pragma unroll
        for (int qq = 0; qq < 4; ++qq) {
          const int rr = w * 64 + rt * 16 + kb * 4 + qq;
          if (rr < PB) {
            const int ii = i0 + rr / KD;
            const int jj = ii - KD + rr % KD;
            const float* Ar = AB + (size_t)ii * HPAD;
            const float* Br = ABB + (size_t)jj * HPAD;
            ushort* hrow = H1blk + (size_t)rr * HPAD;
#pragma unroll
            for (int ct = 0; ct < 10; ++ct) {
              const int col = ct * 16 + l15;
              const float v = acc[rt][ct][qq] + Ar[col] + Br[col];
              hrow[col] = bf16_rne(fmaxf(v, 0.f));
            }
          }
        }
    }  // acc dead here

    // ======== phase 2: out = relu(h1@W2 + b2) @ W3 + b3 ========
    asm volatile("s_waitcnt vmcnt(0)" ::: "memory");  // own H1 stores visible
    const ushort* h1p[4];
#pragma unroll
    for (int rt = 0; rt < 4; ++rt) {
      const int rr = min(w * 64 + rt * 16 + l15, PB - 1);
      h1p[rt] = H1blk + (size_t)rr * HPAD + kb * 8;
    }
    float b2v[10], w3v[10];
#pragma unroll
    for (int ct = 0; ct < 10; ++ct) {
      const int col = ct * 16 + l15;
      b2v[ct] = (col < 150) ? b2[col] : 0.f;
      w3v[ct] = (col < 150) ? W3[col] : 0.f;
    }
    const float b3v = b3[0];

    f32x4 acc2[4][10];
#pragma unroll
    for (int a = 0; a < 4; ++a)
#pragma unroll
      for (int b = 0; b < 10; ++b) acc2[a][b] = (f32x4)(0.f);

    stage_hi(W2_hi, Wb0, w, lane);
    short8 a2[4];
#pragma unroll
    for (int rt = 0; rt < 4; ++rt) a2[rt] = *(const short8*)h1p[rt];

#pragma unroll
    for (int c2 = 0; c2 < NKC2; ++c2) {
      __syncthreads();
      if (c2 < NKC2 - 1)
        stage_hi(W2_hi + (size_t)(c2 + 1) * WCH1, (c2 & 1) ? Wb0 : Wb1, w, lane);
      const ushort* wb = (c2 & 1) ? Wb1 : Wb0;
#pragma unroll
      for (int ct = 0; ct < 10; ++ct) {
        const short8 bh = *(const short8*)&wb[ct * 512 + lswz];
        acc2[0][ct] = mfma16(a2[0], bh, acc2[0][ct]);
        acc2[1][ct] = mfma16(a2[1], bh, acc2[1][ct]);
        acc2[2][ct] = mfma16(a2[2], bh, acc2[2][ct]);
        acc2[3][ct] = mfma16(a2[3], bh, acc2[3][ct]);
      }
      if (c2 < NKC2 - 1) {
#pragma unroll
        for (int rt = 0; rt < 4; ++rt)
          a2[rt] = *(const short8*)(h1p[rt] + (c2 + 1) * 32);
      }
    }
#pragma unroll
    for (int rt = 0; rt < 4; ++rt)
#pragma unroll
      for (int qq = 0; qq < 4; ++qq) {
        float s = 0.f;
#pragma unroll
        for (int ct = 0; ct < 10; ++ct)
          s = fmaf(fmaxf(acc2[rt][ct][qq] + b2v[ct], 0.f), w3v[ct], s);
        s += __shfl_xor(s, 1); s += __shfl_xor(s, 2);
        s += __shfl_xor(s, 4); s += __shfl_xor(s, 8);
        if (l15 == 0) {
          const int rr = w * 64 + rt * 16 + kb * 4 + qq;
          if (rr < PB) out[TD + (size_t)bid * PB + rr] = s + b3v;
        }
      }
  } else {
    // ======== gen: gathered pairs, 128 rows/block, K=128 phases ========
    const int r0 = ((int)blockIdx.x - ND) * 128;
    const int wlim = wlimHead;
    if (tid < 128) {
      int i, j;
      pair_ij(r0 + tid, K, NP, i, j);
      tI[tid] = i; tJ[tid] = j;
    }
    stage_W128(W1c_hi, Wb0, w, lane);
    __syncthreads();

    const int rowA = w * 32 + l15, rowB = rowA + 16;
    const float* gi0 = G + (size_t)tI[rowA] * DP + kb * 8;
    const float* gj0 = G + (size_t)tJ[rowA] * DP + kb * 8;
    const float* gi1 = G + (size_t)tI[rowB] * DP + kb * 8;
    const float* gj1 = G + (size_t)tJ[rowB] * DP + kb * 8;

    {
      f32x4 acc[2][10];
#pragma unroll
      for (int a = 0; a < 2; ++a)
#pragma unroll
        for (int b = 0; b < 10; ++b) acc[a][b] = (f32x4)(0.f);

      for (int c = 0; c < NPH; ++c) {
        if (c) __syncthreads();
        if (c < NPH - 1)
          stage_W128(W1c_hi + (size_t)(c + 1) * 4 * WCH1, (c & 1) ? Wb0 : Wb1,
                     w, lane);
        const ushort* wb = (c & 1) ? Wb1 : Wb0;
#pragma unroll
        for (int ks = 0; ks < 4; ++ks) {
          const int off = c * 128 + ks * 32;
          const short8 a0 =
              mulcvt8(*(const float4*)(gi0 + off), *(const float4*)(gi0 + off + 4),
                      *(const float4*)(gj0 + off), *(const float4*)(gj0 + off + 4));
          const short8 a1 =
              mulcvt8(*(const float4*)(gi1 + off), *(const float4*)(gi1 + off + 4),
                      *(const float4*)(gj1 + off), *(const float4*)(gj1 + off + 4));
          const ushort* wks = wb + ks * WCH1;
#pragma unroll
          for (int ct = 0; ct < 10; ++ct) {
            const short8 bh = *(const short8*)&wks[ct * 512 + lswz];
            acc[0][ct] = mfma16(a0, bh, acc[0][ct]);
            acc[1][ct] = mfma16(a1, bh, acc[1][ct]);
          }
        }
      }

#pragma unroll
      for (int rt = 0; rt < 2; ++rt)
#pragma unroll
        for (int qq = 0; qq < 4; ++qq) {
          const int rr = w * 32 + rt * 16 + kb * 4 + qq;
          const int gr = r0 + rr;
          if (gr < wlim) {
            const float* Ar = AB + (size_t)tI[rr] * HPAD;
            const float* Br = ABB + (size_t)tJ[rr] * HPAD;
            ushort* hrow = H1 + (size_t)gr * HPAD;
#pragma unroll
            for (int ct = 0; ct < 10; ++ct) {
              const int col = ct * 16 + l15;
              const float v = acc[rt][ct][qq] + Ar[col] + Br[col];
              hrow[col] = bf16_rne(fmaxf(v, 0.f));
            }
          }
        }
    }  // acc dead

    // ---- phase 2 ----
    asm volatile("s_waitcnt vmcnt(0)" ::: "memory");
    const ushort* h1p[2];
#pragma unroll
    for (int rt = 0; rt < 2; ++rt) {
      const int gr = min(r0 + w * 32 + rt * 16 + l15, NP - 1);
      h1p[rt] = H1 + (size_t)gr * HPAD + kb * 8;
    }
    float b2v[10], w3v[10];
#pragma unroll
    for (int ct = 0; ct < 10; ++ct) {
      const int col = ct * 16 + l15;
      b2v[ct] = (col < 150) ? b2[col] : 0.f;
      w3v[ct] = (col < 150) ? W3[col] : 0.f;
    }
    const float b3v = b3[0];

    f32x4 acc2[2][10];
#pragma unroll
    for (int a = 0; a < 2; ++a)
#pragma unroll
      for (int b = 0; b < 10; ++b) acc2[a][b] = (f32x4)(0.f);

    stage_hi(W2_hi, Wb0, w, lane);
    short8 a2[2];
#pragma unroll
    for (int rt = 0; rt < 2; ++rt) a2[rt] = *(const short8*)h1p[rt];

#pragma unroll
    for (int c2 = 0; c2 < NKC2; ++c2) {
      __syncthreads();
      if (c2 < NKC2 - 1)
        stage_hi(W2_hi + (size_t)(c2 + 1) * WCH1, (c2 & 1) ? Wb0 : Wb1, w, lane);
      const ushort* wb = (c2 & 1) ? Wb1 : Wb0;
#pragma unroll
      for (int ct = 0; ct < 10; ++ct) {
        const short8 bh = *(const short8*)&wb[ct * 512 + lswz];
        acc2[0][ct] = mfma16(a2[0], bh, acc2[0][ct]);
        acc2[1][ct] = mfma16(a2[1], bh, acc2[1][ct]);
      }
      if (c2 < NKC2 - 1) {
#pragma unroll
        for (int rt = 0; rt < 2; ++rt)
          a2[rt] = *(const short8*)(h1p[rt] + (c2 + 1) * 32);
      }
    }
#pragma unroll
    for (int rt = 0; rt < 2; ++rt)
#pragma unroll
      for (int qq = 0; qq < 4; ++qq) {
        float s = 0.f;
#pragma unroll
        for (int ct = 0; ct < 10; ++ct)
          s = fmaf(fmaxf(acc2[rt][ct][qq] + b2v[ct], 0.f), w3v[ct], s);
        s += __shfl_xor(s, 1); s += __shfl_xor(s, 2);
        s += __shfl_xor(s, 4); s += __shfl_xor(s, 8);
        if (l15 == 0) {
          const int gr = r0 + w * 32 + rt * 16 + kb * 4 + qq;
          if (gr < wlim) out[gr] = s + b3v;
        }
      }
  }
}

extern "C" void kernel_launch(void* const* d_in, const int* in_sizes, int n_in,
                              void* d_out, int out_size, void* d_ws, size_t ws_size,
                              hipStream_t stream) {
  const float* M    = (const float*)d_in[0];
  const int*   pidx = (const int*)d_in[1];
  const float* W1   = (const float*)d_in[3];
  const float* b1   = (const float*)d_in[4];
  const float* W2   = (const float*)d_in[5];
  const float* b2   = (const float*)d_in[6];
  const float* W3   = (const float*)d_in[7];
  const float* b3   = (const float*)d_in[8];
  float* out = (float*)d_out;

  const int P = in_sizes[1];
  const int NP = out_size;
  int K = 50;
  for (int k = 1; k <= P; ++k) {
    const long long np = (long long)k * (k - 1) / 2 + (long long)(P - k) * k;
    if (np == (long long)NP) { K = k; break; }
  }

  // ws: G [P][1280] f32 | AB [2][P][160] f32 | W1ab_hi 2*38*5120 us |
  //     W1c_hi 40*5120 us | W2_hi 5*5120 us | H1 [~101k rows][160] us
  float* G = (float*)d_ws;
  float* AB = G + (size_t)P * DP;
  ushort* W1ab_hi = (ushort*)(AB + (size_t)2 * P * HPAD);
  ushort* W1c_hi = W1ab_hi + (size_t)2 * NKCP * WCH1;
  ushort* W2_hi = W1c_hi + (size_t)NIMG * WCH1;
  ushort* H1 = W2_hi + (size_t)NKC2 * WCH1;

  const int prepN = (2 * NKCP + NIMG + NKC2) * HPAD * 32;
  const int prepB = (prepN + 255) / 256;
  k_prep_gather<<<P + prepB, 256, 0, stream>>>(W1, W2, M, pidx, W1ab_hi,
                                               W1c_hi, W2_hi, G, P);
  dim3 gp((P + 31) / 32, 2);
  k_precomp<<<gp, 256, 0, stream>>>(G, W1ab_hi, b1, AB, P);

  int ND = 0, wlimHead, headB;
  if (K == KD && P > KD && (P - KD) % TI == 0) {
    ND = (P - KD) / TI;                 // 390 dense blocks (pairs >= TD)
    wlimHead = TD;
    headB = (TD + 127) / 128;           // 10 head blocks
  } else {
    wlimHead = NP;
    headB = (NP + 127) / 128;           // full generic coverage
  }
  k_pair<<<ND + headB, 256, 0, stream>>>(G, W1c_hi, W2_hi, AB, b2, W3, b3, H1,
                                         out, P, K, NP, ND, wlimHead);
}

// Round 14
// 116.164 us; speedup vs baseline: 1.4578x; 1.4578x over previous
//
#include <hip/hip_runtime.h>
#include <hip/hip_bf16.h>

// PairwiseScore round 14: R12 base (TI=5, 256thr, fused MLP phase 2) with the
// dense main loop converted to a 3-buffer counted-vmcnt pipeline:
//   stage(c+2) -> vmcnt(4) -> compute(c) -> s_barrier
// Loads stay in flight across barriers (no vmcnt(0) drain per chunk). Only
// global_load_lds ops live in the vmcnt domain inside the loop (G comes from
// LDS), so the count is exact. Gen path / phase 2 / precomp unchanged from R12.
//   h1 = relu(gi@W1a + gj@W1b + (gi.gj)@W1c + b1)   [A/B precomp per mention]
//   out = relu(h1@W2 + b2) @ W3 + b3
// Shapes: M=10000, D=1200(->1216), P=2000, K=50, H=150(->160), NP=98725.

typedef __attribute__((ext_vector_type(8))) short short8;
typedef __attribute__((ext_vector_type(4))) float f32x4;

constexpr int DP    = 1216;      // padded G_DIM (38*32)
constexpr int HPAD  = 160;       // padded hidden
constexpr int NKC   = 38;        // K-chunks of 32 over DP
constexpr int NKC2  = 5;         // K-chunks of 32 over HPAD
constexpr int WCH1  = 5120;      // ushorts per hi-only W chunk image
constexpr int KD    = 50;        // compile-time K
constexpr int TI    = 5;         // i's per dense block
constexpr int PB    = TI * KD;   // 250 pairs per dense block
constexpr int NGR   = KD + TI;   // 55 staged G rows
constexpr int TD    = KD * (KD - 1) / 2;  // 1225 head pairs

// smem layout (bytes): 3 W bufs, 3 G bufs, pair tables
constexpr int OFF_WQ0 = 0;
constexpr int OFF_WQ1 = 10240;
constexpr int OFF_WQ2 = 20480;
constexpr int OFF_GQ0 = 30720;
constexpr int OFF_GQ1 = 38912;
constexpr int OFF_GQ2 = 47104;
constexpr int OFF_TI  = 55296;
constexpr int OFF_TJ  = 55808;
constexpr int SMEM_SZ = 56320;

__device__ __forceinline__ ushort bf16_rne(float x) {
  uint u = __float_as_uint(x);
  u += 0x7FFFu + ((u >> 16) & 1u);
  return (ushort)(u >> 16);
}
__device__ __forceinline__ float bf16f(ushort h) {
  return __uint_as_float((uint)h << 16);
}
__device__ __forceinline__ f32x4 mfma16(short8 a, short8 b, f32x4 c) {
  return __builtin_amdgcn_mfma_f32_16x16x32_bf16(a, b, c, 0, 0, 0);
}
__device__ __forceinline__ void g2lds16(const void* g, void* l) {
  __builtin_amdgcn_global_load_lds(
      (const __attribute__((address_space(1))) void*)g,
      (__attribute__((address_space(3))) void*)l, 16, 0, 0);
}
// stage a 10240B hi-only W chunk (4 waves; w<2 issue 3 ops, w>=2 issue 2)
__device__ __forceinline__ void stage_hi(const ushort* gs, ushort* lb,
                                         int w, int lane) {
  const char* g = (const char*)gs + w * 1024 + lane * 16;
  char* l = (char*)lb + w * 1024;
  g2lds16(g, l);
  g2lds16(g + 4096, l + 4096);
  if (w < 2) g2lds16(g + 8192, l + 8192);
}
// stage the 55-row x 32-col f32 G slice (chunk c), inverse-XOR source (rule #21)
// 2 issues per lane.
__device__ __forceinline__ void stage_G5(const float* __restrict__ G, int gw0,
                                         int c, float* buf, int w, int lane) {
#pragma unroll
  for (int r = 0; r < 2; ++r) {
    const int slot = r * 256 + w * 64 + lane;
    int row = slot >> 3, grp = slot & 7;
    row = min(row, NGR - 1);
    const float* src =
        G + (size_t)(gw0 + row) * DP + c * 32 + ((grp ^ (row & 7)) << 2);
    g2lds16(src, (char*)buf + (r * 256 + w * 64) * 16);  // wave-uniform base
  }
}
// products (8 elems) -> bf16 RNE via hardware cvt_pk
__device__ __forceinline__ short8 mulcvt8(float4 a0, float4 a1, float4 b0,
                                          float4 b1) {
  float p[8] = {a0.x * b0.x, a0.y * b0.y, a0.z * b0.z, a0.w * b0.w,
                a1.x * b1.x, a1.y * b1.y, a1.z * b1.z, a1.w * b1.w};
  uint r[4];
#pragma unroll
  for (int e = 0; e < 4; ++e) {
    __hip_bfloat162 t = __float22bfloat162_rn(make_float2(p[2 * e], p[2 * e + 1]));
    r[e] = *(uint*)&t;
  }
  uint4 h = make_uint4(r[0], r[1], r[2], r[3]);
  return *(short8*)&h;
}
// exact hi/lo split of raw values (precomp path)
__device__ __forceinline__ void split1(const float* a, short8& hi, short8& lo) {
  const float4 a0 = *(const float4*)a, a1 = *(const float4*)(a + 4);
  float p[8] = {a0.x, a0.y, a0.z, a0.w, a1.x, a1.y, a1.z, a1.w};
  uint h[4], l[4];
#pragma unroll
  for (int e = 0; e < 4; ++e) {
    uint u0 = __float_as_uint(p[2 * e]), u1 = __float_as_uint(p[2 * e + 1]);
    float r0 = p[2 * e] - __uint_as_float(u0 & 0xffff0000u);
    float r1 = p[2 * e + 1] - __uint_as_float(u1 & 0xffff0000u);
    h[e] = __builtin_amdgcn_perm(u1, u0, 0x07060302u);
    l[e] = __builtin_amdgcn_perm(__float_as_uint(r1), __float_as_uint(r0),
                                 0x07060302u);
  }
  uint4 hu = make_uint4(h[0], h[1], h[2], h[3]);
  uint4 lu = make_uint4(l[0], l[1], l[2], l[3]);
  hi = *(short8*)&hu; lo = *(short8*)&lu;
}
__device__ __forceinline__ void pair_ij(int r, int K, int NP, int& i, int& j) {
  if (r >= NP) { i = 1; j = 0; return; }
  const int T = K * (K - 1) / 2;
  if (r < T) {
    int ii = (int)((1.0f + sqrtf(1.0f + 8.0f * (float)r)) * 0.5f);
    while (ii * (ii - 1) / 2 > r) --ii;
    while ((ii + 1) * ii / 2 <= r) ++ii;
    i = ii; j = r - ii * (ii - 1) / 2;
  } else {
    const int rp = r - T, q = rp / K;
    i = K + q; j = i - K + (rp - q * K);
  }
}

// ---------- k_prep_gather: fused weight prep + G gather ----------
__global__ void k_prep_gather(const float* __restrict__ W1,
                              const float* __restrict__ W2,
                              const float* __restrict__ M,
                              const int* __restrict__ pidx,
                              ushort* __restrict__ W1ab_hi,
                              ushort* __restrict__ W1c_hi,
                              ushort* __restrict__ W2_hi,
                              float* __restrict__ G, int P) {
  if ((int)blockIdx.x < P) {
    const int i = blockIdx.x;
    const int r = pidx[i];
    const float4* src = reinterpret_cast<const float4*>(M + (size_t)r * 1200);
    float4* dst = reinterpret_cast<float4*>(G + (size_t)i * DP);
    for (int t = threadIdx.x; t < DP / 4; t += blockDim.x)
      dst[t] = (t < 300) ? src[t] : make_float4(0.f, 0.f, 0.f, 0.f);
    return;
  }
  const int NAB = 2 * NKC * HPAD * 32;
  const int NC = NKC * HPAD * 32;
  int idx = (blockIdx.x - P) * 256 + threadIdx.x;
  if (idx < NAB) {
    int s = idx / NC, r1 = idx % NC;
    int c = r1 / (HPAD * 32), r2 = r1 % (HPAD * 32);
    int col = r2 >> 5, kk = r2 & 31;
    int k = c * 32 + kk;
    float v = (k < 1200 && col < 150) ? W1[((size_t)s * 1200 + k) * 150 + col] : 0.f;
    int i0 = (col * 32 + kk) ^ ((col & 7) << 3);
    W1ab_hi[(size_t)(s * NKC + c) * WCH1 + i0] = bf16_rne(v);
  } else if (idx < NAB + NC) {
    int r1 = idx - NAB;
    int c = r1 / (HPAD * 32), r2 = r1 % (HPAD * 32);
    int col = r2 >> 5, kk = r2 & 31;
    int k = c * 32 + kk;
    float v = (k < 1200 && col < 150)
                  ? W1[((size_t)2 * 1200 + k) * 150 + col] : 0.f;
    int i0 = (col * 32 + kk) ^ ((col & 7) << 3);
    W1c_hi[(size_t)c * WCH1 + i0] = bf16_rne(v);
  } else {
    int r1 = idx - NAB - NC;
    if (r1 < NKC2 * HPAD * 32) {
      int c = r1 / (HPAD * 32), r2 = r1 % (HPAD * 32);
      int col = r2 >> 5, kk = r2 & 31;
      int k = c * 32 + kk;
      float v = (k < 150 && col < 150) ? W2[(size_t)k * 150 + col] : 0.f;
      int i0 = (col * 32 + kk) ^ ((col & 7) << 3);
      W2_hi[(size_t)c * WCH1 + i0] = bf16_rne(v);
    }
  }
}

// ---------- k_precomp: AB[slab][r][col] = G[r]@W1slab (+b1 if slab0), 2-term ----------
__global__ __launch_bounds__(256, 4) void k_precomp(
    const float* __restrict__ G, const ushort* __restrict__ W1ab_hi,
    const float* __restrict__ b1, float* __restrict__ AB, int P) {
  __shared__ __align__(16) ushort Wb[2][WCH1];
  const int tid = threadIdx.x, lane = tid & 63, w = tid >> 6;
  const int l15 = lane & 15, kb = lane >> 4;
  const int rt = w & 1, ch = w >> 1;
  const int r0 = blockIdx.x * 32;
  const int slab = blockIdx.y;
  const ushort* wsrc = W1ab_hi + (size_t)slab * NKC * WCH1;

  const int row = min(r0 + rt * 16 + l15, P - 1);
  const float* g = G + (size_t)row * DP + kb * 8;
  const int lbase = (l15 * 32 + kb * 8) ^ ((l15 & 7) << 3);

  f32x4 acc[5];
#pragma unroll
  for (int b = 0; b < 5; ++b) acc[b] = (f32x4)(0.f);

  stage_hi(wsrc, Wb[0], w, lane);
  short8 ah, al;
  split1(g, ah, al);

  for (int c = 0; c < NKC; ++c) {
    __syncthreads();
    if (c < NKC - 1)
      stage_hi(wsrc + (size_t)(c + 1) * WCH1, Wb[(c + 1) & 1], w, lane);
    const ushort* wb = Wb[c & 1];
#pragma unroll
    for (int ct = 0; ct < 5; ++ct) {
      const short8 bh = *(const short8*)&wb[(ch * 5 + ct) * 512 + lbase];
      acc[ct] = mfma16(ah, bh, acc[ct]);
      acc[ct] = mfma16(al, bh, acc[ct]);
    }
    if (c < NKC - 1) split1(g + (c + 1) * 32, ah, al);
  }
  float* outp = AB + (size_t)slab * P * HPAD;
#pragma unroll
  for (int q = 0; q < 4; ++q) {
    const int r = r0 + rt * 16 + kb * 4 + q;
    if (r < P) {
#pragma unroll
      for (int ct = 0; ct < 5; ++ct) {
        const int col = (ch * 5 + ct) * 16 + l15;
        float v = acc[ct][q];
        if (slab == 0 && col < 150) v += b1[col];
        outp[(size_t)r * HPAD + col] = v;
      }
    }
  }
}

// ---------- k_pair: dense (bx<ND) + gen head (bx>=ND); phase2 MLP fused ----------
__global__ __launch_bounds__(256, 2) void k_pair(
    const float* __restrict__ G, const ushort* __restrict__ W1c_hi,
    const ushort* __restrict__ W2_hi, const float* __restrict__ AB,
    const float* __restrict__ b2, const float* __restrict__ W3,
    const float* __restrict__ b3, ushort* __restrict__ H1,
    float* __restrict__ out, int P, int K, int NP, int ND, int wlimHead) {
  __shared__ __align__(16) char smem[SMEM_SZ];
  ushort* Wq0 = (ushort*)(smem + OFF_WQ0);
  ushort* Wq1 = (ushort*)(smem + OFF_WQ1);
  ushort* Wq2 = (ushort*)(smem + OFF_WQ2);
  float*  Gq0 = (float*)(smem + OFF_GQ0);
  float*  Gq1 = (float*)(smem + OFF_GQ1);
  float*  Gq2 = (float*)(smem + OFF_GQ2);
  int* tI = (int*)(smem + OFF_TI);
  int* tJ = (int*)(smem + OFF_TJ);

  const int tid = threadIdx.x, lane = tid & 63, w = tid >> 6;
  const int l15 = lane & 15, kb = lane >> 4;
  const int lswz = (l15 * 32 + kb * 8) ^ ((l15 & 7) << 3);
  const float* ABB = AB + (size_t)P * HPAD;

  if ((int)blockIdx.x < ND) {
    // ======== dense: TI=5 i's, 250 pairs, 4 waves x 4 rt x 16 rows ========
    const int q8 = ND >> 3, r8 = ND & 7;
    const int xcd = blockIdx.x & 7, sidx = blockIdx.x >> 3;
    const int bid = (xcd < r8) ? xcd * (q8 + 1) + sidx
                               : r8 * (q8 + 1) + (xcd - r8) * q8 + sidx;
    const int i0 = KD + bid * TI;
    const int gw0 = i0 - KD;
    ushort* H1blk = H1 + (size_t)(TD + (size_t)bid * PB) * HPAD;

    uint sI[4], sJ[4];
#pragma unroll
    for (int rt = 0; rt < 4; ++rt) {
      const int q = min(w * 64 + rt * 16 + l15, PB - 1);
      const int li = KD + q / KD, lj = q / KD + q % KD;
      sI[rt] = li * 8 + ((2 * kb) ^ (li & 7));
      sJ[rt] = lj * 8 + ((2 * kb) ^ (lj & 7));
    }

    {
      f32x4 acc[4][10];
#pragma unroll
      for (int a = 0; a < 4; ++a)
#pragma unroll
        for (int b = 0; b < 10; ++b) acc[a][b] = (f32x4)(0.f);

      // prologue: stage chunks 0,1; certify 0 landed for all waves
      stage_G5(G, gw0, 0, Gq0, w, lane);
      stage_hi(W1c_hi, Wq0, w, lane);
      stage_G5(G, gw0, 1, Gq1, w, lane);
      stage_hi(W1c_hi + (size_t)1 * WCH1, Wq1, w, lane);
      __builtin_amdgcn_sched_barrier(0);
      asm volatile("s_waitcnt vmcnt(4)" ::: "memory");
      __builtin_amdgcn_s_barrier();
      __builtin_amdgcn_sched_barrier(0);

      // per-chunk: stage(c+2) -> vmcnt(VM) -> compute(c) -> s_barrier
#define D_ITER(CI, GCUR, WCUR, GN, WN, VM)                                     \
  do {                                                                         \
    if ((CI) + 2 < NKC) {                                                      \
      stage_G5(G, gw0, (CI) + 2, (GN), w, lane);                               \
      stage_hi(W1c_hi + (size_t)((CI) + 2) * WCH1, (WN), w, lane);             \
    }                                                                          \
    __builtin_amdgcn_sched_barrier(0);                                         \
    asm volatile("s_waitcnt vmcnt(" #VM ")" ::: "memory");                     \
    __builtin_amdgcn_sched_barrier(0);                                         \
    {                                                                          \
      const float4* gp_ = (const float4*)(GCUR);                               \
      const ushort* wb_ = (WCUR);                                              \
      short8 a_[4];                                                            \
      _Pragma("unroll")                                                        \
      for (int rt = 0; rt < 4; ++rt) {                                         \
        const uint si = sI[rt], sj = sJ[rt];                                   \
        a_[rt] = mulcvt8(gp_[si], gp_[si ^ 1], gp_[sj], gp_[sj ^ 1]);          \
      }                                                                        \
      _Pragma("unroll")                                                        \
      for (int ct = 0; ct < 10; ++ct) {                                        \
        const short8 bh = *(const short8*)&wb_[ct * 512 + lswz];               \
        acc[0][ct] = mfma16(a_[0], bh, acc[0][ct]);                            \
        acc[1][ct] = mfma16(a_[1], bh, acc[1][ct]);                            \
        acc[2][ct] = mfma16(a_[2], bh, acc[2][ct]);                            \
        acc[3][ct] = mfma16(a_[3], bh, acc[3][ct]);                            \
      }                                                                        \
    }                                                                          \
    __builtin_amdgcn_s_barrier();                                              \
  } while (0)

      for (int t = 0; t < 12; ++t) {
        const int c = t * 3;
        D_ITER(c,     Gq0, Wq0, Gq2, Wq2, 4);
        D_ITER(c + 1, Gq1, Wq1, Gq0, Wq0, 4);
        D_ITER(c + 2, Gq2, Wq2, Gq1, Wq1, 4);
      }
      D_ITER(36, Gq0, Wq0, Gq2, Wq2, 0);
      D_ITER(37, Gq1, Wq1, Gq2, Wq2, 0);
#undef D_ITER

      // ---- phase1 epilogue: h1 = relu(acc + A[i] + B[j]) -> H1 (last acc use) ----
#pragma unroll
      for (int rt = 0; rt < 4; ++rt)
#pragma unroll
        for (int qq = 0; qq < 4; ++qq) {
          const int rr = w * 64 + rt * 16 + kb * 4 + qq;
          if (rr < PB) {
            const int ii = i0 + rr / KD;
            const int jj = ii - KD + rr % KD;
            const float* Ar = AB + (size_t)ii * HPAD;
            const float* Br = ABB + (size_t)jj * HPAD;
            ushort* hrow = H1blk + (size_t)rr * HPAD;
#pragma unroll
            for (int ct = 0; ct < 10; ++ct) {
              const int col = ct * 16 + l15;
              const float v = acc[rt][ct][qq] + Ar[col] + Br[col];
              hrow[col] = bf16_rne(fmaxf(v, 0.f));
            }
          }
        }
    }  // acc dead here

    // ======== phase 2: out = relu(h1@W2 + b2) @ W3 + b3 ========
    asm volatile("s_waitcnt vmcnt(0)" ::: "memory");  // own H1 stores visible
    const ushort* h1p[4];
#pragma unroll
    for (int rt = 0; rt < 4; ++rt) {
      const int rr = min(w * 64 + rt * 16 + l15, PB - 1);
      h1p[rt] = H1blk + (size_t)rr * HPAD + kb * 8;
    }
    float b2v[10], w3v[10];
#pragma unroll
    for (int ct = 0; ct < 10; ++ct) {
      const int col = ct * 16 + l15;
      b2v[ct] = (col < 150) ? b2[col] : 0.f;
      w3v[ct] = (col < 150) ? W3[col] : 0.f;
    }
    const float b3v = b3[0];

    f32x4 acc2[4][10];
#pragma unroll
    for (int a = 0; a < 4; ++a)
#pragma unroll
      for (int b = 0; b < 10; ++b) acc2[a][b] = (f32x4)(0.f);

    stage_hi(W2_hi, Wq0, w, lane);
    short8 a2[4];
#pragma unroll
    for (int rt = 0; rt < 4; ++rt) a2[rt] = *(const short8*)h1p[rt];

#pragma unroll
    for (int c2 = 0; c2 < NKC2; ++c2) {
      __syncthreads();
      if (c2 < NKC2 - 1)
        stage_hi(W2_hi + (size_t)(c2 + 1) * WCH1, (c2 & 1) ? Wq0 : Wq1, w, lane);
      const ushort* wb = (c2 & 1) ? Wq1 : Wq0;
#pragma unroll
      for (int ct = 0; ct < 10; ++ct) {
        const short8 bh = *(const short8*)&wb[ct * 512 + lswz];
        acc2[0][ct] = mfma16(a2[0], bh, acc2[0][ct]);
        acc2[1][ct] = mfma16(a2[1], bh, acc2[1][ct]);
        acc2[2][ct] = mfma16(a2[2], bh, acc2[2][ct]);
        acc2[3][ct] = mfma16(a2[3], bh, acc2[3][ct]);
      }
      if (c2 < NKC2 - 1) {
#pragma unroll
        for (int rt = 0; rt < 4; ++rt)
          a2[rt] = *(const short8*)(h1p[rt] + (c2 + 1) * 32);
      }
    }
#pragma unroll
    for (int rt = 0; rt < 4; ++rt)
#pragma unroll
      for (int qq = 0; qq < 4; ++qq) {
        float s = 0.f;
#pragma unroll
        for (int ct = 0; ct < 10; ++ct)
          s = fmaf(fmaxf(acc2[rt][ct][qq] + b2v[ct], 0.f), w3v[ct], s);
        s += __shfl_xor(s, 1); s += __shfl_xor(s, 2);
        s += __shfl_xor(s, 4); s += __shfl_xor(s, 8);
        if (l15 == 0) {
          const int rr = w * 64 + rt * 16 + kb * 4 + qq;
          if (rr < PB) out[TD + (size_t)bid * PB + rr] = s + b3v;
        }
      }
  } else {
    // ======== gen: gathered pairs, 128 rows/block (unchanged from R12) ========
    const int r0 = ((int)blockIdx.x - ND) * 128;
    const int wlim = wlimHead;
    if (tid < 128) {
      int i, j;
      pair_ij(r0 + tid, K, NP, i, j);
      tI[tid] = i; tJ[tid] = j;
    }
    stage_hi(W1c_hi, Wq0, w, lane);
    __syncthreads();

    const int rowA = w * 32 + l15, rowB = rowA + 16;
    const float* gi0 = G + (size_t)tI[rowA] * DP + kb * 8;
    const float* gj0 = G + (size_t)tJ[rowA] * DP + kb * 8;
    const float* gi1 = G + (size_t)tI[rowB] * DP + kb * 8;
    const float* gj1 = G + (size_t)tJ[rowB] * DP + kb * 8;

    {
      f32x4 acc[2][10];
#pragma unroll
      for (int a = 0; a < 2; ++a)
#pragma unroll
        for (int b = 0; b < 10; ++b) acc[a][b] = (f32x4)(0.f);

      float4 x00 = *(const float4*)gi0, x01 = *(const float4*)(gi0 + 4);
      float4 y00 = *(const float4*)gj0, y01 = *(const float4*)(gj0 + 4);
      float4 x10 = *(const float4*)gi1, x11 = *(const float4*)(gi1 + 4);
      float4 y10 = *(const float4*)gj1, y11 = *(const float4*)(gj1 + 4);

#pragma unroll 2
      for (int c = 0; c < NKC; ++c) {
        if (c) __syncthreads();
        if (c < NKC - 1)
          stage_hi(W1c_hi + (size_t)(c + 1) * WCH1, (c & 1) ? Wq0 : Wq1, w, lane);
        const short8 a0 = mulcvt8(x00, x01, y00, y01);
        const short8 a1 = mulcvt8(x10, x11, y10, y11);
        if (c < NKC - 1) {
          const int cn = c + 1;
          x00 = *(const float4*)(gi0 + cn * 32); x01 = *(const float4*)(gi0 + cn * 32 + 4);
          y00 = *(const float4*)(gj0 + cn * 32); y01 = *(const float4*)(gj0 + cn * 32 + 4);
          x10 = *(const float4*)(gi1 + cn * 32); x11 = *(const float4*)(gi1 + cn * 32 + 4);
          y10 = *(const float4*)(gj1 + cn * 32); y11 = *(const float4*)(gj1 + cn * 32 + 4);
        }
        const ushort* wb = (c & 1) ? Wq1 : Wq0;
#pragma unroll
        for (int ct = 0; ct < 10; ++ct) {
          const short8 bh = *(const short8*)&wb[ct * 512 + lswz];
          acc[0][ct] = mfma16(a0, bh, acc[0][ct]);
          acc[1][ct] = mfma16(a1, bh, acc[1][ct]);
        }
      }

#pragma unroll
      for (int rt = 0; rt < 2; ++rt)
#pragma unroll
        for (int qq = 0; qq < 4; ++qq) {
          const int rr = w * 32 + rt * 16 + kb * 4 + qq;
          const int gr = r0 + rr;
          if (gr < wlim) {
            const float* Ar = AB + (size_t)tI[rr] * HPAD;
            const float* Br = ABB + (size_t)tJ[rr] * HPAD;
            ushort* hrow = H1 + (size_t)gr * HPAD;
#pragma unroll
            for (int ct = 0; ct < 10; ++ct) {
              const int col = ct * 16 + l15;
              const float v = acc[rt][ct][qq] + Ar[col] + Br[col];
              hrow[col] = bf16_rne(fmaxf(v, 0.f));
            }
          }
        }
    }  // acc dead

    // ---- phase 2 ----
    asm volatile("s_waitcnt vmcnt(0)" ::: "memory");
    const ushort* h1p[2];
#pragma unroll
    for (int rt = 0; rt < 2; ++rt) {
      const int gr = min(r0 + w * 32 + rt * 16 + l15, NP - 1);
      h1p[rt] = H1 + (size_t)gr * HPAD + kb * 8;
    }
    float b2v[10], w3v[10];
#pragma unroll
    for (int ct = 0; ct < 10; ++ct) {
      const int col = ct * 16 + l15;
      b2v[ct] = (col < 150) ? b2[col] : 0.f;
      w3v[ct] = (col < 150) ? W3[col] : 0.f;
    }
    const float b3v = b3[0];

    f32x4 acc2[2][10];
#pragma unroll
    for (int a = 0; a < 2; ++a)
#pragma unroll
      for (int b = 0; b < 10; ++b) acc2[a][b] = (f32x4)(0.f);

    stage_hi(W2_hi, Wq0, w, lane);
    short8 a2[2];
#pragma unroll
    for (int rt = 0; rt < 2; ++rt) a2[rt] = *(const short8*)h1p[rt];

#pragma unroll
    for (int c2 = 0; c2 < NKC2; ++c2) {
      __syncthreads();
      if (c2 < NKC2 - 1)
        stage_hi(W2_hi + (size_t)(c2 + 1) * WCH1, (c2 & 1) ? Wq0 : Wq1, w, lane);
      const ushort* wb = (c2 & 1) ? Wq1 : Wq0;
#pragma unroll
      for (int ct = 0; ct < 10; ++ct) {
        const short8 bh = *(const short8*)&wb[ct * 512 + lswz];
        acc2[0][ct] = mfma16(a2[0], bh, acc2[0][ct]);
        acc2[1][ct] = mfma16(a2[1], bh, acc2[1][ct]);
      }
      if (c2 < NKC2 - 1) {
#pragma unroll
        for (int rt = 0; rt < 2; ++rt)
          a2[rt] = *(const short8*)(h1p[rt] + (c2 + 1) * 32);
      }
    }
#pragma unroll
    for (int rt = 0; rt < 2; ++rt)
#pragma unroll
      for (int qq = 0; qq < 4; ++qq) {
        float s = 0.f;
#pragma unroll
        for (int ct = 0; ct < 10; ++ct)
          s = fmaf(fmaxf(acc2[rt][ct][qq] + b2v[ct], 0.f), w3v[ct], s);
        s += __shfl_xor(s, 1); s += __shfl_xor(s, 2);
        s += __shfl_xor(s, 4); s += __shfl_xor(s, 8);
        if (l15 == 0) {
          const int gr = r0 + w * 32 + rt * 16 + kb * 4 + qq;
          if (gr < wlim) out[gr] = s + b3v;
        }
      }
  }
}

extern "C" void kernel_launch(void* const* d_in, const int* in_sizes, int n_in,
                              void* d_out, int out_size, void* d_ws, size_t ws_size,
                              hipStream_t stream) {
  const float* M    = (const float*)d_in[0];
  const int*   pidx = (const int*)d_in[1];
  const float* W1   = (const float*)d_in[3];
  const float* b1   = (const float*)d_in[4];
  const float* W2   = (const float*)d_in[5];
  const float* b2   = (const float*)d_in[6];
  const float* W3   = (const float*)d_in[7];
  const float* b3   = (const float*)d_in[8];
  float* out = (float*)d_out;

  const int P = in_sizes[1];
  const int NP = out_size;
  int K = 50;
  for (int k = 1; k <= P; ++k) {
    const long long np = (long long)k * (k - 1) / 2 + (long long)(P - k) * k;
    if (np == (long long)NP) { K = k; break; }
  }

  // ws: G [P][1216] f32 | AB [2][P][160] f32 | W1ab_hi 2*38*5120 us |
  //     W1c_hi 38*5120 us | W2_hi 5*5120 us | H1 [NP+pad][160] us
  float* G = (float*)d_ws;
  float* AB = G + (size_t)P * DP;
  ushort* W1ab_hi = (ushort*)(AB + (size_t)2 * P * HPAD);
  ushort* W1c_hi = W1ab_hi + (size_t)2 * NKC * WCH1;
  ushort* W2_hi = W1c_hi + (size_t)NKC * WCH1;
  ushort* H1 = W2_hi + (size_t)NKC2 * WCH1;

  const int prepN = (2 * NKC + NKC + NKC2) * HPAD * 32;
  const int prepB = (prepN + 255) / 256;
  k_prep_gather<<<P + prepB, 256, 0, stream>>>(W1, W2, M, pidx, W1ab_hi,
                                               W1c_hi, W2_hi, G, P);
  dim3 gp((P + 31) / 32, 2);
  k_precomp<<<gp, 256, 0, stream>>>(G, W1ab_hi, b1, AB, P);

  int ND = 0, wlimHead, headB;
  if (K == KD && P > KD && (P - KD) % TI == 0) {
    ND = (P - KD) / TI;                 // 390 dense blocks (pairs >= TD)
    wlimHead = TD;
    headB = (TD + 127) / 128;           // 10 head blocks
  } else {
    wlimHead = NP;
    headB = (NP + 127) / 128;           // full generic coverage
  }
  k_pair<<<ND + headB, 256, 0, stream>>>(G, W1c_hi, W2_hi, AB, b2, W3, b3, H1,
                                         out, P, K, NP, ND, wlimHead);
}